// Round 3
// baseline (99.630 us; speedup 1.0000x reference)
//
#include <hip/hip_runtime.h>

#define NPTS 8192
#define NSL 32          // j-slices (256 points each)
#define HF 96.0f

typedef float v4f __attribute__((ext_vector_type(4)));
typedef int   v4i __attribute__((ext_vector_type(4)));

// Workspace layout (bytes):
//   0        : float  nn2p[32][8192]   partial (sqi + min E) per (slice, i)
//   1048576  : u16    rkp [32][8192]   partial pz-rank per (slice, i)  (<=255)
//   1572864  : float2 pxy[8192]        (px,py) sorted by pz
//   1638400  : float  pzs[8192]
//   1671168  : double sum_part[32]     per-block partial sums of nn_dist
//   1671424  : float  sx[8192]         original x*HF   (exact, for k_mid)
//   1704192  : float  sy[8192]
//   1736960  : float  sz[8192]
//   1769728  : float  dx[8192]         -2*x*HF  (exact pow2 scale, for k_nn_rank)
//   1802496  : float  dy[8192]
//   1835264  : float  dz[8192]
//   1868032  : float  ssq[8192]        x^2+y^2+z^2
//   1900800  : u64    skey[8192]       monotone (z, idx) sort key
// Session lessons: coop grid.sync ~100us/sync -> keep separate launches.
// 16-col k_median regressed -> keep 8-col.
// R1: DS vs scalar-load inner loop NEUTRAL => k_nn_rank is VALU-bound; ~80us of
//     the window is the harness 256MiB poison (2x40us fills @84% HBM = roofline).
// R2: packed v4f d2 chain: 107.1 -> 99.2us. Confirms VALU-bound model.
// R3 (this): fold -2 into stored operands + hoist sqi out of the min loop
//     (22 -> 18 VALU insts per 4j); NSL 64->32 + u16 ranks halves k_mid.

// monotone (z, idx) -> u64 key; strict total order, one u64 compare per pair
__device__ __forceinline__ unsigned long long zkey(float z, int idx) {
    unsigned u = __float_as_uint(z);
    unsigned m = (unsigned)((int)u >> 31) | 0x80000000u;  // neg: FFFFFFFF, pos: 80000000
    return ((unsigned long long)(u ^ m) << 13) | (unsigned)idx;
}

// SoA prep: 32 blocks x 256.
__global__ __launch_bounds__(256) void k_soa(const float* __restrict__ pts,
                                             float* __restrict__ sx,
                                             float* __restrict__ sy,
                                             float* __restrict__ sz,
                                             float* __restrict__ dx,
                                             float* __restrict__ dy,
                                             float* __restrict__ dz,
                                             float* __restrict__ ssq,
                                             unsigned long long* __restrict__ skey) {
    const int i = blockIdx.x * 256 + threadIdx.x;
    const float x = pts[3 * i + 0] * HF;
    const float y = pts[3 * i + 1] * HF;
    const float z = pts[3 * i + 2] * HF;
    sx[i] = x; sy[i] = y; sz[i] = z;
    dx[i] = -2.0f * x; dy[i] = -2.0f * y; dz[i] = -2.0f * z;  // exact (pow2 scale)
    ssq[i] = x * x + y * y + z * z;
    skey[i] = zkey(z, i);
}

// grid (32 i-blocks, 32 j-slices of 256), block 256 -> 1024 blocks, 4/CU.
// j-operands wave-uniform -> scalar-cache loads. Inner chain: E_j = Q_j +
// xi*(-2xj) + yi*(-2yj) + zi*(-2zj) = 3 pk_fma; d2_j = sqi + E_j with sqi
// hoisted out of the min (fp add with common addend is monotone -> exact).
__global__ __launch_bounds__(256) void k_nn_rank(const float* __restrict__ sx,
                                                 const float* __restrict__ sy,
                                                 const float* __restrict__ sz,
                                                 const float* __restrict__ dx,
                                                 const float* __restrict__ dy,
                                                 const float* __restrict__ dz,
                                                 const float* __restrict__ ssq,
                                                 const unsigned long long* __restrict__ skey,
                                                 float* __restrict__ nn2p,
                                                 unsigned short* __restrict__ rkp) {
    const int tid = threadIdx.x;
    const int bx = blockIdx.x, by = blockIdx.y;
    const int i = bx * 256 + tid;

    const float xi = sx[i], yi = sy[i], zi = sz[i], sqi = ssq[i];
    const unsigned long long ki = skey[i];

    // uniform (wave-invariant) j-slice base pointers, 16B-aligned
    const v4f* __restrict__ vx = (const v4f*)dx + by * 64;
    const v4f* __restrict__ vy = (const v4f*)dy + by * 64;
    const v4f* __restrict__ vz = (const v4f*)dz + by * 64;
    const v4f* __restrict__ vq = (const v4f*)ssq + by * 64;
    const ulonglong2* __restrict__ vk = (const ulonglong2*)skey + by * 128;

    v4f mn4 = {3.0e38f, 3.0e38f, 3.0e38f, 3.0e38f};
    int rk = 0;
    // self-pair occurs iff this j-slice covers this i-block (block-uniform).
    const bool has_self = (by == bx);
    if (!has_self) {
        #pragma unroll 8
        for (int kb = 0; kb < 64; ++kb) {
            const v4f X = vx[kb], Y = vy[kb], Z = vz[kb], Q = vq[kb];
            const ulonglong2 K0 = vk[2 * kb], K1 = vk[2 * kb + 1];
            v4f E = ((Q + xi * X) + yi * Y) + zi * Z;   // 3x pk_fma
            mn4 = __builtin_elementwise_min(mn4, E);
            rk += (int)(K0.x < ki) + (int)(K0.y < ki) + (int)(K1.x < ki) + (int)(K1.y < ki);
        }
    } else {
        const int self_k = tid;   // j - j0 of the self pair (per-lane)
        const v4i sk4 = {self_k, self_k, self_k, self_k};
        #pragma unroll 8
        for (int kb = 0; kb < 64; ++kb) {
            const v4f X = vx[kb], Y = vy[kb], Z = vz[kb], Q = vq[kb];
            const ulonglong2 K0 = vk[2 * kb], K1 = vk[2 * kb + 1];
            v4f E = ((Q + xi * X) + yi * Y) + zi * Z;
            const int e = kb * 4;
            const v4i ev = {e, e + 1, e + 2, e + 3};
            const v4f big = {3.0e38f, 3.0e38f, 3.0e38f, 3.0e38f};
            E = (ev == sk4) ? big : E;   // exclude self (elementwise cndmask)
            mn4 = __builtin_elementwise_min(mn4, E);
            rk += (int)(K0.x < ki) + (int)(K0.y < ki) + (int)(K1.x < ki) + (int)(K1.y < ki);
        }
    }
    // horizontal min, then add hoisted sqi (monotone -> same value as per-elem)
    const float mnE = fminf(fminf(mn4.x, mn4.y), fminf(mn4.z, mn4.w));
    nn2p[by * NPTS + i] = sqi + mnE;        // coalesced, written exactly once
    rkp [by * NPTS + i] = (unsigned short)rk;
}

// grid 32, block 256. Reduce partials -> nn_dist + total rank; scatter into
// pz-sorted order; per-block double partial sum of nn_dist.
__global__ __launch_bounds__(256) void k_mid(const float* __restrict__ sx,
                                             const float* __restrict__ sy,
                                             const float* __restrict__ sz,
                                             const float* __restrict__ nn2p,
                                             const unsigned short* __restrict__ rkp,
                                             float2* __restrict__ pxy,
                                             float* __restrict__ pzs,
                                             double* __restrict__ sum_part) {
    const int t = threadIdx.x;
    const int i = blockIdx.x * 256 + t;
    float mn = 3.0e38f;
    int rk = 0;
    #pragma unroll 8
    for (int s = 0; s < NSL; ++s) {
        mn = fminf(mn, nn2p[s * NPTS + i]);   // coalesced across threads
        rk += rkp[s * NPTS + i];
    }
    // clamp commutes with min across slices: min_s max(m_s,0) == max(min_s,0)
    const float nnd = sqrtf(fmaxf(mn, 0.0f));
    pxy[rk] = make_float2(sx[i], sy[i]);
    pzs[rk] = sz[i];

    double acc = (double)nnd;
    #pragma unroll
    for (int off = 32; off > 0; off >>= 1) acc += __shfl_down(acc, off, 64);
    __shared__ double sw[4];
    if ((t & 63) == 0) sw[t >> 6] = acc;
    __syncthreads();
    if (t == 0) sum_part[blockIdx.x] = sw[0] + sw[1] + sw[2] + sw[3];
}

// One block per (row, group of 8 cols): 12x96 blocks. Thread t owns point
// 256k+t of chunk k (pz-sorted) -> coalesced float2 loads. Membership as
// per-wave 64-bit ballots in LDS; rank selection per-wave in the epilogue.
// delta2 finalized per-block from the 32 double partials (deterministic ->
// identical in every block).
// NOTE: replicates reference exactly: px upper bound uses Yr (row-uniform), not Xr.
__global__ __launch_bounds__(256) void k_median(const float2* __restrict__ pxy,
                                                const float* __restrict__ pzs,
                                                const double* __restrict__ sum_part,
                                                float* __restrict__ out) {
    __shared__ unsigned long long bal[8][4][32];  // [cell][wave][chunk]
    __shared__ float s_dd;
    const int t = threadIdx.x;
    const int lane = t & 63;
    const int w = t >> 6;
    const int row = blockIdx.y;      // 96
    const int cg = blockIdx.x;       // 12 col-groups of 8
    if (t == 0) {
        double s = 0.0;
        #pragma unroll
        for (int b = 0; b < 32; ++b) s += sum_part[b];
        float mean = (float)(s / (double)NPTS);
        float avg = 3.0f * mean;     // M_FACTOR * mean
        s_dd = 3.0f * avg;           // M_FACTOR * avg
    }
    __syncthreads();
    const float d = s_dd;
    const float Yf = (float)(row - 48);
    const float ylo = Yf - d, yhi = Yf + d, xhi = Yf + d;
    float xlo[8];
    #pragma unroll
    for (int c = 0; c < 8; ++c) xlo[c] = (float)(cg * 8 + c - 48) - d;

    #pragma unroll 4
    for (int k = 0; k < 32; ++k) {
        float2 p = pxy[(k << 8) + t];
        bool pre = (p.y >= ylo) && (p.y <= yhi) && (p.x <= xhi);
        unsigned long long b[8];
        #pragma unroll
        for (int c = 0; c < 8; ++c) b[c] = __ballot(pre && (p.x >= xlo[c]));
        if (lane == 0) {
            #pragma unroll
            for (int c = 0; c < 8; ++c) bal[c][w][k] = b[c];
        }
    }
    __syncthreads();

    // wave w handles cells 2w and 2w+1; lanes 0..31 each own one chunk
    #pragma unroll
    for (int c2 = 0; c2 < 2; ++c2) {
        const int c = w * 2 + c2;
        const int l = (lane < 32) ? lane : 31;
        const unsigned long long bw0 = bal[c][0][l];
        const unsigned long long bw1 = bal[c][1][l];
        const unsigned long long bw2 = bal[c][2][l];
        const unsigned long long bw3 = bal[c][3][l];
        const int cnt = __popcll(bw0) + __popcll(bw1) + __popcll(bw2) + __popcll(bw3);
        const int cl = (lane < 32) ? cnt : 0;
        int incl = cl;
        #pragma unroll
        for (int off = 1; off < 64; off <<= 1) {
            int v = __shfl_up(incl, off, 64);
            if (lane >= off) incl += v;
        }
        const int ct = __shfl(incl, 63, 64);  // total count c
        const int og = row * 96 + cg * 8 + c;
        if (ct == 0) {
            if (lane == 0) out[og] = 0.0f;
            continue;
        }
        const int excl = incl - cl;
        float vv[2];
        #pragma unroll
        for (int sel = 0; sel < 2; ++sel) {
            const int target = sel ? (ct >> 1) : ((ct - 1) >> 1);
            const bool pred = (lane < 32) && (target >= excl) && (target < excl + cl);
            unsigned long long bm = __ballot(pred);
            int src = __ffsll(bm) - 1;  // exactly one lane holds the target
            float val = 0.0f;
            if (pred) {
                int r = target - excl;
                int pc0 = __popcll(bw0), pc1 = __popcll(bw1), pc2 = __popcll(bw2);
                unsigned long long x;
                int base;
                if (r < pc0)              { x = bw0; base = 0; }
                else if (r < pc0 + pc1)   { x = bw1; base = 64;  r -= pc0; }
                else if (r < pc0+pc1+pc2) { x = bw2; base = 128; r -= pc0 + pc1; }
                else                      { x = bw3; base = 192; r -= pc0 + pc1 + pc2; }
                for (int q = 0; q < r; ++q) x &= x - 1;  // drop r lowest set bits
                val = pzs[(l << 8) + base + (__ffsll(x) - 1)];
            }
            vv[sel] = __shfl(val, src, 64);
        }
        if (lane == 0) {
            float med = 0.5f * (vv[0] + vv[1]);
            out[og] = (med + 48.0f) * (1.0f / 96.0f);
        }
    }
}

extern "C" void kernel_launch(void* const* d_in, const int* in_sizes, int n_in,
                              void* d_out, int out_size, void* d_ws, size_t ws_size,
                              hipStream_t stream) {
    const float* pts = (const float*)d_in[0];
    float* out = (float*)d_out;

    char* ws = (char*)d_ws;
    float* nn2p          = (float*)(ws + 0);
    unsigned short* rkp  = (unsigned short*)(ws + 1048576);
    float2* pxy          = (float2*)(ws + 1572864);
    float* pzs           = (float*)(ws + 1638400);
    double* sum_part     = (double*)(ws + 1671168);
    float* sx            = (float*)(ws + 1671424);
    float* sy            = (float*)(ws + 1704192);
    float* sz            = (float*)(ws + 1736960);
    float* dx            = (float*)(ws + 1769728);
    float* dy            = (float*)(ws + 1802496);
    float* dz            = (float*)(ws + 1835264);
    float* ssq           = (float*)(ws + 1868032);
    unsigned long long* skey = (unsigned long long*)(ws + 1900800);

    k_soa<<<32, 256, 0, stream>>>(pts, sx, sy, sz, dx, dy, dz, ssq, skey);
    k_nn_rank<<<dim3(32, NSL), 256, 0, stream>>>(sx, sy, sz, dx, dy, dz, ssq, skey, nn2p, rkp);
    k_mid<<<32, 256, 0, stream>>>(sx, sy, sz, nn2p, rkp, pxy, pzs, sum_part);
    k_median<<<dim3(12, 96), 256, 0, stream>>>(pxy, pzs, sum_part, out);
}

// Round 4
// 95.689 us; speedup vs baseline: 1.0412x; 1.0412x over previous
//
#include <hip/hip_runtime.h>

#define NPTS 8192
#define NSL 32          // j-slices (256 points each)
#define HF 96.0f

typedef float v4f __attribute__((ext_vector_type(4)));
typedef int   v4i __attribute__((ext_vector_type(4)));

// Workspace layout (bytes):
//   0        : float  nn2p[32][8192]   partial (sqi + min E) per (slice, i)
//   1048576  : u16    rkp [32][8192]   partial pz-rank per (slice, i)  (<=255)
//   1572864  : float2 pxy[8192]        (px,py) sorted by pz
//   1638400  : float  pzs[8192]
//   1671168  : double sum_part[32]     per-block partial sums of nn_dist
// Session lessons: coop grid.sync ~100us/sync -> keep separate launches.
// 16-col k_median regressed -> keep 8-col.
// R1: DS vs scalar-load inner loop NEUTRAL => k_nn_rank is VALU-bound; ~80us of
//     the window is the harness 256MiB poison (2x40us fills @84-86% HBM = roofline).
// R2: packed v4f d2 chain: 107.1 -> 99.2us. Confirms VALU-bound model.
// R3: folded -2 / hoisted sqi + NSL 64->32: NEUTRAL (99.6) -- d2 trim (~0.8us)
//     offset by lower occupancy. Floors: k_nn_rank ~3.4us (half is the
//     irreducible rank-compare chain), k_mid ~1.5, k_median ~3.5, gaps ~4.
// R4 (this): dispatch consolidation. Fuse SoA prep into k_nn_rank (j-slice
//     computed per-block into LDS; broadcast ds_read_b128 proven neutral in R1);
//     k_mid reads pts directly. 4 -> 3 launches, SoA HBM traffic gone.
//     Per-element arithmetic bit-identical to R3.

// monotone (z, idx) -> u64 key; strict total order, one u64 compare per pair
__device__ __forceinline__ unsigned long long zkey(float z, int idx) {
    unsigned u = __float_as_uint(z);
    unsigned m = (unsigned)((int)u >> 31) | 0x80000000u;  // neg: FFFFFFFF, pos: 80000000
    return ((unsigned long long)(u ^ m) << 13) | (unsigned)idx;
}

// grid (32 i-blocks, 32 j-slices of 256), block 256 -> 1024 blocks.
// j-slice staged in LDS (uniform-address broadcast reads, conflict-free).
// Inner chain per 4j: 3x pk_fma + pk_min + 4x (u64 cmp + addc) -- VALU-minimal.
// sqi hoisted out of the min (fp add with common addend is monotone -> exact).
__global__ __launch_bounds__(256) void k_nn_rank(const float* __restrict__ pts,
                                                 float* __restrict__ nn2p,
                                                 unsigned short* __restrict__ rkp) {
    __shared__ __align__(16) float sX[256], sY[256], sZ[256], sQ[256];
    __shared__ unsigned long long sK[256];
    const int tid = threadIdx.x;
    const int bx = blockIdx.x, by = blockIdx.y;
    const int i = bx * 256 + tid;
    const int j = by * 256 + tid;

    // j-side staging (bit-identical ops to the old k_soa)
    {
        const float xj = pts[3 * j + 0] * HF;
        const float yj = pts[3 * j + 1] * HF;
        const float zj = pts[3 * j + 2] * HF;
        sX[tid] = -2.0f * xj;          // exact (pow2 scale)
        sY[tid] = -2.0f * yj;
        sZ[tid] = -2.0f * zj;
        sQ[tid] = xj * xj + yj * yj + zj * zj;
        sK[tid] = zkey(zj, j);
    }
    // i-side (L1 hits when bx==by)
    const float xi = pts[3 * i + 0] * HF;
    const float yi = pts[3 * i + 1] * HF;
    const float zi = pts[3 * i + 2] * HF;
    const float sqi = xi * xi + yi * yi + zi * zi;
    const unsigned long long ki = zkey(zi, i);
    __syncthreads();

    const v4f* __restrict__ vx = (const v4f*)sX;
    const v4f* __restrict__ vy = (const v4f*)sY;
    const v4f* __restrict__ vz = (const v4f*)sZ;
    const v4f* __restrict__ vq = (const v4f*)sQ;
    const ulonglong2* __restrict__ vk = (const ulonglong2*)sK;

    v4f mn4 = {3.0e38f, 3.0e38f, 3.0e38f, 3.0e38f};
    int rk = 0;
    // self-pair occurs iff this j-slice is this i-block (block-uniform).
    const bool has_self = (by == bx);
    if (!has_self) {
        #pragma unroll 8
        for (int kb = 0; kb < 64; ++kb) {
            const v4f X = vx[kb], Y = vy[kb], Z = vz[kb], Q = vq[kb];
            const ulonglong2 K0 = vk[2 * kb], K1 = vk[2 * kb + 1];
            v4f E = ((Q + xi * X) + yi * Y) + zi * Z;   // 3x pk_fma
            mn4 = __builtin_elementwise_min(mn4, E);
            rk += (int)(K0.x < ki) + (int)(K0.y < ki) + (int)(K1.x < ki) + (int)(K1.y < ki);
        }
    } else {
        const int self_k = tid;   // j - j0 of the self pair (per-lane)
        const v4i sk4 = {self_k, self_k, self_k, self_k};
        #pragma unroll 8
        for (int kb = 0; kb < 64; ++kb) {
            const v4f X = vx[kb], Y = vy[kb], Z = vz[kb], Q = vq[kb];
            const ulonglong2 K0 = vk[2 * kb], K1 = vk[2 * kb + 1];
            v4f E = ((Q + xi * X) + yi * Y) + zi * Z;
            const int e = kb * 4;
            const v4i ev = {e, e + 1, e + 2, e + 3};
            const v4f big = {3.0e38f, 3.0e38f, 3.0e38f, 3.0e38f};
            E = (ev == sk4) ? big : E;   // exclude self (elementwise cndmask)
            mn4 = __builtin_elementwise_min(mn4, E);
            rk += (int)(K0.x < ki) + (int)(K0.y < ki) + (int)(K1.x < ki) + (int)(K1.y < ki);
        }
    }
    // horizontal min, then add hoisted sqi (monotone -> same value as per-elem)
    const float mnE = fminf(fminf(mn4.x, mn4.y), fminf(mn4.z, mn4.w));
    nn2p[by * NPTS + i] = sqi + mnE;        // coalesced, written exactly once
    rkp [by * NPTS + i] = (unsigned short)rk;
}

// grid 32, block 256. Reduce partials -> nn_dist + total rank; scatter into
// pz-sorted order; per-block double partial sum of nn_dist.
__global__ __launch_bounds__(256) void k_mid(const float* __restrict__ pts,
                                             const float* __restrict__ nn2p,
                                             const unsigned short* __restrict__ rkp,
                                             float2* __restrict__ pxy,
                                             float* __restrict__ pzs,
                                             double* __restrict__ sum_part) {
    const int t = threadIdx.x;
    const int i = blockIdx.x * 256 + t;
    float mn = 3.0e38f;
    int rk = 0;
    #pragma unroll 8
    for (int s = 0; s < NSL; ++s) {
        mn = fminf(mn, nn2p[s * NPTS + i]);   // coalesced across threads
        rk += rkp[s * NPTS + i];
    }
    // clamp commutes with min across slices: min_s max(m_s,0) == max(min_s,0)
    const float nnd = sqrtf(fmaxf(mn, 0.0f));
    // bit-identical to old SoA values
    pxy[rk] = make_float2(pts[3 * i + 0] * HF, pts[3 * i + 1] * HF);
    pzs[rk] = pts[3 * i + 2] * HF;

    double acc = (double)nnd;
    #pragma unroll
    for (int off = 32; off > 0; off >>= 1) acc += __shfl_down(acc, off, 64);
    __shared__ double sw[4];
    if ((t & 63) == 0) sw[t >> 6] = acc;
    __syncthreads();
    if (t == 0) sum_part[blockIdx.x] = sw[0] + sw[1] + sw[2] + sw[3];
}

// One block per (row, group of 8 cols): 12x96 blocks. Thread t owns point
// 256k+t of chunk k (pz-sorted) -> coalesced float2 loads. Membership as
// per-wave 64-bit ballots in LDS; rank selection per-wave in the epilogue.
// delta2 finalized per-block from the 32 double partials (deterministic ->
// identical in every block).
// NOTE: replicates reference exactly: px upper bound uses Yr (row-uniform), not Xr.
__global__ __launch_bounds__(256) void k_median(const float2* __restrict__ pxy,
                                                const float* __restrict__ pzs,
                                                const double* __restrict__ sum_part,
                                                float* __restrict__ out) {
    __shared__ unsigned long long bal[8][4][32];  // [cell][wave][chunk]
    __shared__ float s_dd;
    const int t = threadIdx.x;
    const int lane = t & 63;
    const int w = t >> 6;
    const int row = blockIdx.y;      // 96
    const int cg = blockIdx.x;       // 12 col-groups of 8
    if (t == 0) {
        double s = 0.0;
        #pragma unroll
        for (int b = 0; b < 32; ++b) s += sum_part[b];
        float mean = (float)(s / (double)NPTS);
        float avg = 3.0f * mean;     // M_FACTOR * mean
        s_dd = 3.0f * avg;           // M_FACTOR * avg
    }
    __syncthreads();
    const float d = s_dd;
    const float Yf = (float)(row - 48);
    const float ylo = Yf - d, yhi = Yf + d, xhi = Yf + d;
    float xlo[8];
    #pragma unroll
    for (int c = 0; c < 8; ++c) xlo[c] = (float)(cg * 8 + c - 48) - d;

    #pragma unroll 4
    for (int k = 0; k < 32; ++k) {
        float2 p = pxy[(k << 8) + t];
        bool pre = (p.y >= ylo) && (p.y <= yhi) && (p.x <= xhi);
        unsigned long long b[8];
        #pragma unroll
        for (int c = 0; c < 8; ++c) b[c] = __ballot(pre && (p.x >= xlo[c]));
        if (lane == 0) {
            #pragma unroll
            for (int c = 0; c < 8; ++c) bal[c][w][k] = b[c];
        }
    }
    __syncthreads();

    // wave w handles cells 2w and 2w+1; lanes 0..31 each own one chunk
    #pragma unroll
    for (int c2 = 0; c2 < 2; ++c2) {
        const int c = w * 2 + c2;
        const int l = (lane < 32) ? lane : 31;
        const unsigned long long bw0 = bal[c][0][l];
        const unsigned long long bw1 = bal[c][1][l];
        const unsigned long long bw2 = bal[c][2][l];
        const unsigned long long bw3 = bal[c][3][l];
        const int cnt = __popcll(bw0) + __popcll(bw1) + __popcll(bw2) + __popcll(bw3);
        const int cl = (lane < 32) ? cnt : 0;
        int incl = cl;
        #pragma unroll
        for (int off = 1; off < 64; off <<= 1) {
            int v = __shfl_up(incl, off, 64);
            if (lane >= off) incl += v;
        }
        const int ct = __shfl(incl, 63, 64);  // total count c
        const int og = row * 96 + cg * 8 + c;
        if (ct == 0) {
            if (lane == 0) out[og] = 0.0f;
            continue;
        }
        const int excl = incl - cl;
        float vv[2];
        #pragma unroll
        for (int sel = 0; sel < 2; ++sel) {
            const int target = sel ? (ct >> 1) : ((ct - 1) >> 1);
            const bool pred = (lane < 32) && (target >= excl) && (target < excl + cl);
            unsigned long long bm = __ballot(pred);
            int src = __ffsll(bm) - 1;  // exactly one lane holds the target
            float val = 0.0f;
            if (pred) {
                int r = target - excl;
                int pc0 = __popcll(bw0), pc1 = __popcll(bw1), pc2 = __popcll(bw2);
                unsigned long long x;
                int base;
                if (r < pc0)              { x = bw0; base = 0; }
                else if (r < pc0 + pc1)   { x = bw1; base = 64;  r -= pc0; }
                else if (r < pc0+pc1+pc2) { x = bw2; base = 128; r -= pc0 + pc1; }
                else                      { x = bw3; base = 192; r -= pc0 + pc1 + pc2; }
                for (int q = 0; q < r; ++q) x &= x - 1;  // drop r lowest set bits
                val = pzs[(l << 8) + base + (__ffsll(x) - 1)];
            }
            vv[sel] = __shfl(val, src, 64);
        }
        if (lane == 0) {
            float med = 0.5f * (vv[0] + vv[1]);
            out[og] = (med + 48.0f) * (1.0f / 96.0f);
        }
    }
}

extern "C" void kernel_launch(void* const* d_in, const int* in_sizes, int n_in,
                              void* d_out, int out_size, void* d_ws, size_t ws_size,
                              hipStream_t stream) {
    const float* pts = (const float*)d_in[0];
    float* out = (float*)d_out;

    char* ws = (char*)d_ws;
    float* nn2p          = (float*)(ws + 0);
    unsigned short* rkp  = (unsigned short*)(ws + 1048576);
    float2* pxy          = (float2*)(ws + 1572864);
    float* pzs           = (float*)(ws + 1638400);
    double* sum_part     = (double*)(ws + 1671168);

    k_nn_rank<<<dim3(32, NSL), 256, 0, stream>>>(pts, nn2p, rkp);
    k_mid<<<32, 256, 0, stream>>>(pts, nn2p, rkp, pxy, pzs, sum_part);
    k_median<<<dim3(12, 96), 256, 0, stream>>>(pxy, pzs, sum_part, out);
}